// Round 1
// baseline (687.186 us; speedup 1.0000x reference)
//
#include <hip/hip_runtime.h>

typedef unsigned short ushort_t;
typedef unsigned int uint32;
typedef __attribute__((ext_vector_type(8))) short short8;
typedef __attribute__((ext_vector_type(4))) float f32x4;

static __device__ __forceinline__ ushort_t f2bf(float f) {
  uint32 u = __builtin_bit_cast(uint32, f);
  u += 0x7fffu + ((u >> 16) & 1u);   // round-to-nearest-even
  return (ushort_t)(u >> 16);
}
static __device__ __forceinline__ float bf2f(ushort_t h) {
  return __builtin_bit_cast(float, (uint32)h << 16);
}

// ---------------------------------------------------------------------------
// Elementwise: out_bf16 = bf16(a [+ b]) , processes 4 floats/thread
// ---------------------------------------------------------------------------
__global__ void addcvt_kernel(const float* __restrict__ a, const float* __restrict__ b,
                              ushort_t* __restrict__ o, int n4) {
  int i = blockIdx.x * 256 + threadIdx.x;
  if (i >= n4) return;
  float4 va = reinterpret_cast<const float4*>(a)[i];
  if (b != nullptr) {
    float4 vb = reinterpret_cast<const float4*>(b)[i];
    va.x += vb.x; va.y += vb.y; va.z += vb.z; va.w += vb.w;
  }
  ushort4 u;
  u.x = f2bf(va.x); u.y = f2bf(va.y); u.z = f2bf(va.z); u.w = f2bf(va.w);
  reinterpret_cast<ushort4*>(o)[i] = u;
}

// ---------------------------------------------------------------------------
// Tiled bf16 GEMM:  C[M,N] = A[M,K] @ Bt[N,K]^T (+bias) , 128x128 tile, 4 waves
// MODE 0: E = exp(acc+bias) -> bf16 out, atomicAdd column sums into Z[b*1024+col]
// MODE 1: bf16 out = acc+bias
// MODE 2: fp32 out = acc+bias, per-batch Bt (batch = blockIdx.y / btBatchTiles)
// LDS tiles K-contiguous rows of 64 bf16 (128B), XOR-swizzled: byte ^= (row&7)<<4
// ---------------------------------------------------------------------------
template<int MODE>
__global__ __launch_bounds__(256, 2)
void gemm_bf16(const ushort_t* __restrict__ A, const ushort_t* __restrict__ Bt,
               const float* __restrict__ bias, void* __restrict__ Cout,
               float* __restrict__ Z, int M, int N, int K,
               int btBatchTiles, long long btBatchStride) {
  __shared__ ushort_t As[8192];   // 128 x 64 bf16
  __shared__ ushort_t Bs[8192];
  const int t = threadIdx.x;
  const int w = t >> 6, lane = t & 63;
  const int l15 = lane & 15, l4 = lane >> 4;
  const int mBase = blockIdx.y * 128, nBase = blockIdx.x * 128;
  const ushort_t* Btb = Bt;
  if (MODE == 2 && btBatchTiles > 0)
    Btb += (long long)(blockIdx.y / btBatchTiles) * btBatchStride;

  f32x4 acc[4][4];
#pragma unroll
  for (int i = 0; i < 4; i++)
#pragma unroll
    for (int j = 0; j < 4; j++) acc[i][j] = (f32x4){0.f, 0.f, 0.f, 0.f};

  const int wm = (w >> 1) * 64, wn = (w & 1) * 64;

  for (int k0 = 0; k0 < K; k0 += 64) {
    // ---- stage global -> LDS (each thread: 4x 16B for A, 4x 16B for B) ----
#pragma unroll
    for (int i = 0; i < 4; i++) {
      int idx = i * 256 + t;
      int row = idx >> 3, g = idx & 7;
      uint4 va = *reinterpret_cast<const uint4*>(A + (size_t)(mBase + row) * K + k0 + g * 8);
      *reinterpret_cast<uint4*>(reinterpret_cast<char*>(As) + row * 128 + ((g * 16) ^ ((row & 7) << 4))) = va;
      uint4 vb = *reinterpret_cast<const uint4*>(Btb + (size_t)(nBase + row) * K + k0 + g * 8);
      *reinterpret_cast<uint4*>(reinterpret_cast<char*>(Bs) + row * 128 + ((g * 16) ^ ((row & 7) << 4))) = vb;
    }
    __syncthreads();
    // ---- compute: 2 k-steps of 32, 16 MFMA each ----
#pragma unroll
    for (int kk = 0; kk < 2; kk++) {
      short8 af[4], bfr[4];
      const int kb = kk * 64 + l4 * 16;
#pragma unroll
      for (int f = 0; f < 4; f++) {
        int rowA = wm + f * 16 + l15;
        af[f] = *reinterpret_cast<const short8*>(reinterpret_cast<const char*>(As) + rowA * 128 + (kb ^ ((rowA & 7) << 4)));
        int rowB = wn + f * 16 + l15;
        bfr[f] = *reinterpret_cast<const short8*>(reinterpret_cast<const char*>(Bs) + rowB * 128 + (kb ^ ((rowB & 7) << 4)));
      }
#pragma unroll
      for (int fm = 0; fm < 4; fm++)
#pragma unroll
        for (int fn = 0; fn < 4; fn++)
          acc[fm][fn] = __builtin_amdgcn_mfma_f32_16x16x32_bf16(af[fm], bfr[fn], acc[fm][fn], 0, 0, 0);
    }
    __syncthreads();
  }

  // ---- epilogue; C/D layout: col = lane&15, row = (lane>>4)*4 + reg ----
  if (MODE == 0) {
    ushort_t* E = (ushort_t*)Cout;
#pragma unroll
    for (int fn = 0; fn < 4; fn++) {
      int col = nBase + wn + fn * 16 + l15;
      float bcol = bias[col];
      float csum = 0.f;
#pragma unroll
      for (int fm = 0; fm < 4; fm++) {
#pragma unroll
        for (int r = 0; r < 4; r++) {
          int row = mBase + wm + fm * 16 + l4 * 4 + r;
          float e = __expf(acc[fm][fn][r] + bcol);
          E[(size_t)row * N + col] = f2bf(e);
          csum += e;
        }
      }
      csum += __shfl_xor(csum, 16);
      csum += __shfl_xor(csum, 32);
      if (l4 == 0) atomicAdd(&Z[(blockIdx.y >> 5) * 1024 + col], csum);
    }
  } else if (MODE == 1) {
    ushort_t* C = (ushort_t*)Cout;
#pragma unroll
    for (int fn = 0; fn < 4; fn++) {
      int col = nBase + wn + fn * 16 + l15;
      float bcol = bias[col];
#pragma unroll
      for (int fm = 0; fm < 4; fm++)
#pragma unroll
        for (int r = 0; r < 4; r++) {
          int row = mBase + wm + fm * 16 + l4 * 4 + r;
          C[(size_t)row * N + col] = f2bf(acc[fm][fn][r] + bcol);
        }
    }
  } else {
    float* C = (float*)Cout;
#pragma unroll
    for (int fn = 0; fn < 4; fn++) {
      int col = nBase + wn + fn * 16 + l15;
      float bcol = bias[col];
#pragma unroll
      for (int fm = 0; fm < 4; fm++)
#pragma unroll
        for (int r = 0; r < 4; r++) {
          int row = mBase + wm + fm * 16 + l4 * 4 + r;
          C[(size_t)row * N + col] = acc[fm][fn][r] + bcol;
        }
    }
  }
}

// ---------------------------------------------------------------------------
// Per-(row,head) softmax over 64 contiguous channels. One wave per unit.
// units = rows*8.  Input/output bf16 [rows,512].
// ---------------------------------------------------------------------------
__global__ void softmax64_kernel(const ushort_t* __restrict__ kraw,
                                 ushort_t* __restrict__ ks, int units) {
  int unit = blockIdx.x * 4 + (threadIdx.x >> 6);
  int lane = threadIdx.x & 63;
  if (unit >= units) return;
  int row = unit >> 3, h = unit & 7;
  size_t idx = (size_t)row * 512 + h * 64 + lane;
  float x = bf2f(kraw[idx]);
  float m = x;
#pragma unroll
  for (int off = 32; off >= 1; off >>= 1) m = fmaxf(m, __shfl_xor(m, off));
  float e = __expf(x - m);
  float s = e;
#pragma unroll
  for (int off = 32; off >= 1; off >>= 1) s += __shfl_xor(s, off);
  ks[idx] = f2bf(e / s);
}

// ---------------------------------------------------------------------------
// ctx[b,h,d,e] = sum_n ks[b,n,h*64+d] * v[b,n,h*64+e].  One block per (b,h).
// ctxOut already offset for the branch; layout [(b*8+h)][64][64] fp32.
// ---------------------------------------------------------------------------
__global__ void ctx_kernel(const ushort_t* __restrict__ ks, const ushort_t* __restrict__ v,
                           float* __restrict__ ctxOut, int Nk) {
  __shared__ float ks_s[64][65];
  __shared__ float v_s[64][65];
  int b = blockIdx.x >> 3, h = blockIdx.x & 7;
  int t = threadIdx.x;
  int td = t & 15, te = t >> 4;
  float acc[4][4];
#pragma unroll
  for (int i = 0; i < 4; i++)
#pragma unroll
    for (int j = 0; j < 4; j++) acc[i][j] = 0.f;
  size_t rowBase = (size_t)b * Nk;
  for (int n0 = 0; n0 < Nk; n0 += 64) {
#pragma unroll
    for (int i = 0; i < 16; i++) {
      int idx = i * 256 + t;
      int n = idx >> 6, d = idx & 63;
      size_t g = (rowBase + n0 + n) * 512 + h * 64 + d;
      ks_s[n][d] = bf2f(ks[g]);
      v_s[n][d] = bf2f(v[g]);
    }
    __syncthreads();
    for (int n = 0; n < 64; n++) {
      float kv[4], vv[4];
#pragma unroll
      for (int dd = 0; dd < 4; dd++) kv[dd] = ks_s[n][td * 4 + dd];
#pragma unroll
      for (int ee = 0; ee < 4; ee++) vv[ee] = v_s[n][te * 4 + ee];
#pragma unroll
      for (int dd = 0; dd < 4; dd++)
#pragma unroll
        for (int ee = 0; ee < 4; ee++) acc[dd][ee] += kv[dd] * vv[ee];
    }
    __syncthreads();
  }
#pragma unroll
  for (int dd = 0; dd < 4; dd++)
#pragma unroll
    for (int ee = 0; ee < 4; ee++)
      ctxOut[((size_t)(b * 8 + h) * 64 + td * 4 + dd) * 64 + te * 4 + ee] = acc[dd][ee];
}

// ---------------------------------------------------------------------------
// Fold: Mt[b][j][c] = (sum_e ctx[branch,b,h,d,e]*Wr[j, branch*512+h*64+e]) / Z[b,c]
// c = branch*512 + h*64 + d.  One block per (b, branch, h).
// ---------------------------------------------------------------------------
__global__ void fold_kernel(const float* __restrict__ ctx, const float* __restrict__ Wr,
                            const float* __restrict__ Z, ushort_t* __restrict__ Mt) {
  __shared__ float ctx_s[64][65];
  __shared__ float wr_s[64][65];
  __shared__ float zinv[64];
  int b = blockIdx.x >> 4, u = blockIdx.x & 15;
  int branch = u >> 3, h = u & 7;
  int t = threadIdx.x;
  int cbase = branch * 512 + h * 64;
#pragma unroll
  for (int i = 0; i < 16; i++) {
    int idx = i * 256 + t;
    int d = idx >> 6, e = idx & 63;
    ctx_s[d][e] = ctx[(((size_t)branch * 64 + b * 8 + h) * 64 + d) * 64 + e];
  }
  if (t < 64) zinv[t] = 1.0f / Z[b * 1024 + cbase + t];
  __syncthreads();
  int d = t & 63, jg = t >> 6;
  for (int j0 = 0; j0 < 512; j0 += 64) {
#pragma unroll
    for (int i = 0; i < 16; i++) {
      int idx = i * 256 + t;
      int jl = idx >> 6, e = idx & 63;
      wr_s[jl][e] = Wr[(size_t)(j0 + jl) * 1024 + cbase + e];
    }
    __syncthreads();
#pragma unroll
    for (int ii = 0; ii < 16; ii++) {
      int jl = jg * 16 + ii;
      float dot = 0.f;
#pragma unroll
      for (int e = 0; e < 64; e++) dot += ctx_s[d][e] * wr_s[jl][e];
      Mt[((size_t)b * 512 + j0 + jl) * 1024 + cbase + d] = f2bf(dot * zinv[d]);
    }
    __syncthreads();
  }
}

// ---------------------------------------------------------------------------
extern "C" void kernel_launch(void* const* d_in, const int* in_sizes, int n_in,
                              void* d_out, int out_size, void* d_ws, size_t ws_size,
                              hipStream_t stream) {
  const float* f2 = (const float*)d_in[0];
  const float* f3 = (const float*)d_in[1];
  const float* f4 = (const float*)d_in[2];
  const float* f2pe = (const float*)d_in[3];
  const float* f3pe = (const float*)d_in[4];
  const float* f4pe = (const float*)d_in[5];
  const float* Wq1 = (const float*)d_in[6];
  const float* bq1 = (const float*)d_in[7];
  const float* Wk1 = (const float*)d_in[8];
  const float* bk1 = (const float*)d_in[9];
  const float* Wv1 = (const float*)d_in[10];
  const float* bv1 = (const float*)d_in[11];
  const float* Wq2 = (const float*)d_in[12];
  const float* bq2 = (const float*)d_in[13];
  const float* Wk2 = (const float*)d_in[14];
  const float* bk2 = (const float*)d_in[15];
  const float* Wv2 = (const float*)d_in[16];
  const float* bv2 = (const float*)d_in[17];
  const float* Wr = (const float*)d_in[18];
  const float* br = (const float*)d_in[19];

  char* ws = (char*)d_ws;
  // Region 0: E bf16 [32768,1024]
  ushort_t* E = (ushort_t*)(ws + 0);                       // 67,108,864 B
  // Region 1 (reused over time): f2p -> {f3p,f3b,f4p,f4b} -> {ks3,ks4,ctx}
  char* R1 = ws + 67108864;                                // 33,554,432 B
  ushort_t* f2p = (ushort_t*)R1;
  ushort_t* f3p = (ushort_t*)R1;
  ushort_t* f3b = (ushort_t*)(R1 + 8388608);
  ushort_t* f4p = (ushort_t*)(R1 + 16777216);
  ushort_t* f4b = (ushort_t*)(R1 + 18874368);
  ushort_t* ks3 = (ushort_t*)R1;
  ushort_t* ks4 = (ushort_t*)(R1 + 8388608);
  float* ctx = (float*)(R1 + 10485760);                    // 2,097,152 B fp32
  // Region 2: raw kv GEMM outputs (bf16)
  char* R2 = ws + 100663296;                               // 20,971,520 B
  ushort_t* k3r = (ushort_t*)R2;
  ushort_t* v3b = (ushort_t*)(R2 + 8388608);
  ushort_t* k4r = (ushort_t*)(R2 + 16777216);
  ushort_t* v4b = (ushort_t*)(R2 + 18874368);
  // Region 3: weights bf16, Mt, Z, bqcat
  char* R3 = ws + 121634816;
  ushort_t* WqB = (ushort_t*)R3;                           // 1,048,576
  ushort_t* Wk1B = (ushort_t*)(R3 + 1048576);
  ushort_t* Wv1B = (ushort_t*)(R3 + 1572864);
  ushort_t* Wk2B = (ushort_t*)(R3 + 2097152);
  ushort_t* Wv2B = (ushort_t*)(R3 + 2621440);
  ushort_t* Mt = (ushort_t*)(R3 + 3145728);                // 8,388,608
  float* Z = (float*)(R3 + 11534336);                      // 32,768
  float* bqc = (float*)(R3 + 11567104);                    // 4,096

  // ---- prep ----
  hipMemsetAsync(Z, 0, 8 * 1024 * sizeof(float), stream);
  hipMemcpyAsync(bqc, bq1, 512 * sizeof(float), hipMemcpyDeviceToDevice, stream);
  hipMemcpyAsync(bqc + 512, bq2, 512 * sizeof(float), hipMemcpyDeviceToDevice, stream);

  addcvt_kernel<<<16384, 256, 0, stream>>>(f2, f2pe, f2p, 4194304);          // f2p
  addcvt_kernel<<<256, 256, 0, stream>>>(Wq1, nullptr, WqB, 65536);          // Wq cat
  addcvt_kernel<<<256, 256, 0, stream>>>(Wq2, nullptr, WqB + 262144, 65536);
  addcvt_kernel<<<256, 256, 0, stream>>>(Wk1, nullptr, Wk1B, 65536);
  addcvt_kernel<<<256, 256, 0, stream>>>(Wv1, nullptr, Wv1B, 65536);
  addcvt_kernel<<<256, 256, 0, stream>>>(Wk2, nullptr, Wk2B, 65536);
  addcvt_kernel<<<256, 256, 0, stream>>>(Wv2, nullptr, Wv2B, 65536);

  // ---- G1: E = exp(f2p @ WqB^T + bqc), Z colsums ----
  gemm_bf16<0><<<dim3(8, 256), 256, 0, stream>>>(f2p, WqB, bqc, E, Z,
                                                 32768, 1024, 512, 0, 0);

  // ---- kv inputs (reuse R1 — f2p is dead now) ----
  addcvt_kernel<<<4096, 256, 0, stream>>>(f3, f3pe, f3p, 1048576);
  addcvt_kernel<<<4096, 256, 0, stream>>>(f3, nullptr, f3b, 1048576);
  addcvt_kernel<<<1024, 256, 0, stream>>>(f4, f4pe, f4p, 262144);
  addcvt_kernel<<<1024, 256, 0, stream>>>(f4, nullptr, f4b, 262144);

  // ---- kv GEMMs ----
  gemm_bf16<1><<<dim3(4, 64), 256, 0, stream>>>(f3p, Wk1B, bk1, k3r, nullptr,
                                                8192, 512, 512, 0, 0);
  gemm_bf16<1><<<dim3(4, 64), 256, 0, stream>>>(f3b, Wv1B, bv1, v3b, nullptr,
                                                8192, 512, 512, 0, 0);
  gemm_bf16<1><<<dim3(4, 16), 256, 0, stream>>>(f4p, Wk2B, bk2, k4r, nullptr,
                                                2048, 512, 512, 0, 0);
  gemm_bf16<1><<<dim3(4, 16), 256, 0, stream>>>(f4b, Wv2B, bv2, v4b, nullptr,
                                                2048, 512, 512, 0, 0);

  // ---- channel softmax of k (per row, per 64-ch head group) ----
  softmax64_kernel<<<16384, 256, 0, stream>>>(k3r, ks3, 65536);
  softmax64_kernel<<<4096, 256, 0, stream>>>(k4r, ks4, 16384);

  // ---- ctx = ks^T v  per (b,h), both branches ----
  ctx_kernel<<<64, 256, 0, stream>>>(ks3, v3b, ctx, 1024);
  ctx_kernel<<<64, 256, 0, stream>>>(ks4, v4b, ctx + 262144, 256);

  // ---- fold ctx, Wr, 1/Z into per-batch Mt[b][j][c] ----
  fold_kernel<<<128, 256, 0, stream>>>(ctx, Wr, Z, Mt);

  // ---- G2: out = E @ Mt^T + br  (per-batch Bt) ----
  gemm_bf16<2><<<dim3(4, 256), 256, 0, stream>>>(E, Mt, br, (float*)d_out, nullptr,
                                                 32768, 512, 1024, 32, 524288);
}

// Round 2
// 324.618 us; speedup vs baseline: 2.1169x; 2.1169x over previous
//
#include <hip/hip_runtime.h>

typedef unsigned short ushort_t;
typedef unsigned int uint32;
typedef __attribute__((ext_vector_type(8))) short short8;
typedef __attribute__((ext_vector_type(4))) float f32x4;

static __device__ __forceinline__ ushort_t f2bf(float f) {
  uint32 u = __builtin_bit_cast(uint32, f);
  u += 0x7fffu + ((u >> 16) & 1u);   // round-to-nearest-even
  return (ushort_t)(u >> 16);
}
static __device__ __forceinline__ float bf2f(ushort_t h) {
  return __builtin_bit_cast(float, (uint32)h << 16);
}

// ---------------------------------------------------------------------------
// Elementwise: out_bf16 = bf16(a [+ b]) , processes 4 floats/thread
// ---------------------------------------------------------------------------
__global__ void addcvt_kernel(const float* __restrict__ a, const float* __restrict__ b,
                              ushort_t* __restrict__ o, int n4) {
  int i = blockIdx.x * 256 + threadIdx.x;
  if (i >= n4) return;
  float4 va = reinterpret_cast<const float4*>(a)[i];
  if (b != nullptr) {
    float4 vb = reinterpret_cast<const float4*>(b)[i];
    va.x += vb.x; va.y += vb.y; va.z += vb.z; va.w += vb.w;
  }
  ushort4 u;
  u.x = f2bf(va.x); u.y = f2bf(va.y); u.z = f2bf(va.z); u.w = f2bf(va.w);
  reinterpret_cast<ushort4*>(o)[i] = u;
}

// ---------------------------------------------------------------------------
// Tiled bf16 GEMM:  C[M,N] = A[M,K] @ Bt[N,K]^T (+bias) , 128x128 tile, 4 waves
// MODE 0: E = exp(acc+bias) -> bf16 out, atomicAdd column sums into Z[b*1024+col]
// MODE 1: bf16 out = acc+bias
// MODE 2: fp32 out = acc+bias, per-batch Bt (batch = blockIdx.y / btBatchTiles)
// LDS tiles K-contiguous rows of 64 bf16 (128B), XOR-swizzled: byte ^= (row&7)<<4
// ---------------------------------------------------------------------------
template<int MODE>
__global__ __launch_bounds__(256, 2)
void gemm_bf16(const ushort_t* __restrict__ A, const ushort_t* __restrict__ Bt,
               const float* __restrict__ bias, void* __restrict__ Cout,
               float* __restrict__ Z, int M, int N, int K,
               int btBatchTiles, long long btBatchStride) {
  __shared__ ushort_t As[8192];   // 128 x 64 bf16
  __shared__ ushort_t Bs[8192];
  const int t = threadIdx.x;
  const int w = t >> 6, lane = t & 63;
  const int l15 = lane & 15, l4 = lane >> 4;
  const int mBase = blockIdx.y * 128, nBase = blockIdx.x * 128;
  const ushort_t* Btb = Bt;
  if (MODE == 2 && btBatchTiles > 0)
    Btb += (long long)(blockIdx.y / btBatchTiles) * btBatchStride;

  f32x4 acc[4][4];
#pragma unroll
  for (int i = 0; i < 4; i++)
#pragma unroll
    for (int j = 0; j < 4; j++) acc[i][j] = (f32x4){0.f, 0.f, 0.f, 0.f};

  const int wm = (w >> 1) * 64, wn = (w & 1) * 64;

  for (int k0 = 0; k0 < K; k0 += 64) {
    // ---- stage global -> LDS (each thread: 4x 16B for A, 4x 16B for B) ----
#pragma unroll
    for (int i = 0; i < 4; i++) {
      int idx = i * 256 + t;
      int row = idx >> 3, g = idx & 7;
      uint4 va = *reinterpret_cast<const uint4*>(A + (size_t)(mBase + row) * K + k0 + g * 8);
      *reinterpret_cast<uint4*>(reinterpret_cast<char*>(As) + row * 128 + ((g * 16) ^ ((row & 7) << 4))) = va;
      uint4 vb = *reinterpret_cast<const uint4*>(Btb + (size_t)(nBase + row) * K + k0 + g * 8);
      *reinterpret_cast<uint4*>(reinterpret_cast<char*>(Bs) + row * 128 + ((g * 16) ^ ((row & 7) << 4))) = vb;
    }
    __syncthreads();
    // ---- compute: 2 k-steps of 32, 16 MFMA each ----
#pragma unroll
    for (int kk = 0; kk < 2; kk++) {
      short8 af[4], bfr[4];
      const int kb = kk * 64 + l4 * 16;
#pragma unroll
      for (int f = 0; f < 4; f++) {
        int rowA = wm + f * 16 + l15;
        af[f] = *reinterpret_cast<const short8*>(reinterpret_cast<const char*>(As) + rowA * 128 + (kb ^ ((rowA & 7) << 4)));
        int rowB = wn + f * 16 + l15;
        bfr[f] = *reinterpret_cast<const short8*>(reinterpret_cast<const char*>(Bs) + rowB * 128 + (kb ^ ((rowB & 7) << 4)));
      }
#pragma unroll
      for (int fm = 0; fm < 4; fm++)
#pragma unroll
        for (int fn = 0; fn < 4; fn++)
          acc[fm][fn] = __builtin_amdgcn_mfma_f32_16x16x32_bf16(af[fm], bfr[fn], acc[fm][fn], 0, 0, 0);
    }
    __syncthreads();
  }

  // ---- epilogue; C/D layout: col = lane&15, row = (lane>>4)*4 + reg ----
  if (MODE == 0) {
    ushort_t* E = (ushort_t*)Cout;
#pragma unroll
    for (int fn = 0; fn < 4; fn++) {
      int col = nBase + wn + fn * 16 + l15;
      float bcol = bias[col];
      float csum = 0.f;
#pragma unroll
      for (int fm = 0; fm < 4; fm++) {
#pragma unroll
        for (int r = 0; r < 4; r++) {
          int row = mBase + wm + fm * 16 + l4 * 4 + r;
          float e = __expf(acc[fm][fn][r] + bcol);
          E[(size_t)row * N + col] = f2bf(e);
          csum += e;
        }
      }
      csum += __shfl_xor(csum, 16);
      csum += __shfl_xor(csum, 32);
      if (l4 == 0) atomicAdd(&Z[(blockIdx.y >> 5) * 1024 + col], csum);
    }
  } else if (MODE == 1) {
    ushort_t* C = (ushort_t*)Cout;
#pragma unroll
    for (int fn = 0; fn < 4; fn++) {
      int col = nBase + wn + fn * 16 + l15;
      float bcol = bias[col];
#pragma unroll
      for (int fm = 0; fm < 4; fm++)
#pragma unroll
        for (int r = 0; r < 4; r++) {
          int row = mBase + wm + fm * 16 + l4 * 4 + r;
          C[(size_t)row * N + col] = f2bf(acc[fm][fn][r] + bcol);
        }
    }
  } else {
    float* C = (float*)Cout;
#pragma unroll
    for (int fn = 0; fn < 4; fn++) {
      int col = nBase + wn + fn * 16 + l15;
      float bcol = bias[col];
#pragma unroll
      for (int fm = 0; fm < 4; fm++)
#pragma unroll
        for (int r = 0; r < 4; r++) {
          int row = mBase + wm + fm * 16 + l4 * 4 + r;
          C[(size_t)row * N + col] = acc[fm][fn][r] + bcol;
        }
    }
  }
}

// ---------------------------------------------------------------------------
// Per-(row,head) softmax over 64 contiguous channels. One wave per unit.
// units = rows*8.  Input/output bf16 [rows,512].
// ---------------------------------------------------------------------------
__global__ void softmax64_kernel(const ushort_t* __restrict__ kraw,
                                 ushort_t* __restrict__ ks, int units) {
  int unit = blockIdx.x * 4 + (threadIdx.x >> 6);
  int lane = threadIdx.x & 63;
  if (unit >= units) return;
  int row = unit >> 3, h = unit & 7;
  size_t idx = (size_t)row * 512 + h * 64 + lane;
  float x = bf2f(kraw[idx]);
  float m = x;
#pragma unroll
  for (int off = 32; off >= 1; off >>= 1) m = fmaxf(m, __shfl_xor(m, off));
  float e = __expf(x - m);
  float s = e;
#pragma unroll
  for (int off = 32; off >= 1; off >>= 1) s += __shfl_xor(s, off);
  ks[idx] = f2bf(e / s);
}

// ---------------------------------------------------------------------------
// ctx[bh,d,e] += sum_{n in chunk} ks[b,n,h*64+d] * v[b,n,h*64+e]
// grid.x = B*8*nChunks, each chunk covers 256 rows. fp32 atomicAdd into ctxOut
// (pre-zeroed). Register-tiled 4x4 outer product, float4 LDS reads.
// ---------------------------------------------------------------------------
__global__ __launch_bounds__(256)
void ctx_kernel(const ushort_t* __restrict__ ks, const ushort_t* __restrict__ v,
                float* __restrict__ ctxOut, int Nk, int nChunks) {
  __shared__ float ks_s[64][68];
  __shared__ float v_s[64][68];
  int bh = blockIdx.x / nChunks;
  int chunk = blockIdx.x - bh * nChunks;
  int b = bh >> 3, h = bh & 7;
  int t = threadIdx.x;
  int td = t & 15, te = t >> 4;
  float acc[4][4] = {};
  size_t rowBase = (size_t)b * Nk + chunk * 256;
  for (int n0 = 0; n0 < 256; n0 += 64) {
#pragma unroll
    for (int i = 0; i < 16; i++) {
      int idx = i * 256 + t;
      int n = idx >> 6, d = idx & 63;
      size_t g = (rowBase + n0 + n) * 512 + h * 64 + d;
      ks_s[n][d] = bf2f(ks[g]);
      v_s[n][d] = bf2f(v[g]);
    }
    __syncthreads();
#pragma unroll 8
    for (int n = 0; n < 64; n++) {
      float4 cv = *reinterpret_cast<const float4*>(&ks_s[n][td * 4]);
      float4 vv = *reinterpret_cast<const float4*>(&v_s[n][te * 4]);
      float ca[4] = {cv.x, cv.y, cv.z, cv.w};
      float va[4] = {vv.x, vv.y, vv.z, vv.w};
#pragma unroll
      for (int i = 0; i < 4; i++)
#pragma unroll
        for (int j = 0; j < 4; j++) acc[i][j] += ca[i] * va[j];
    }
    __syncthreads();
  }
  float* dst = ctxOut + (size_t)bh * 4096;
#pragma unroll
  for (int i = 0; i < 4; i++)
#pragma unroll
    for (int j = 0; j < 4; j++)
      atomicAdd(&dst[(td * 4 + i) * 64 + te * 4 + j], acc[i][j]);
}

// ---------------------------------------------------------------------------
// Fold: Mt[b][j][c] = (sum_e ctx[branch,b,h,d,e]*Wr[j, branch*512+h*64+e]) / Z[b,c]
// c = branch*512 + h*64 + d. grid = 1024 blocks: b(8) x branch(2) x h(8) x jc(8),
// each block computes 64 j x 64 d. Register-tiled 4x4 outer product.
// ---------------------------------------------------------------------------
__global__ __launch_bounds__(256)
void fold_kernel(const float* __restrict__ ctx, const float* __restrict__ Wr,
                 const float* __restrict__ Z, ushort_t* __restrict__ Mt) {
  __shared__ float ctxT[64][68];   // [e][d]
  __shared__ float wrT[64][68];    // [e][jl]
  __shared__ float zinv[64];
  int blk = blockIdx.x;
  int jc = blk & 7;
  int h = (blk >> 3) & 7;
  int branch = (blk >> 6) & 1;
  int b = blk >> 7;
  int t = threadIdx.x;
  int cbase = branch * 512 + h * 64;
  const float* csrc = ctx + (size_t)(branch * 64 + b * 8 + h) * 4096;
#pragma unroll
  for (int i = 0; i < 16; i++) {
    int idx = i * 256 + t;
    int d = idx >> 6, e = idx & 63;
    ctxT[e][d] = csrc[d * 64 + e];
  }
#pragma unroll
  for (int i = 0; i < 16; i++) {
    int idx = i * 256 + t;
    int jl = idx >> 6, e = idx & 63;
    wrT[e][jl] = Wr[(size_t)(jc * 64 + jl) * 1024 + cbase + e];
  }
  if (t < 64) zinv[t] = 1.0f / Z[b * 1024 + cbase + t];
  __syncthreads();
  int td = t & 15, tj = t >> 4;
  float acc[4][4] = {};   // [d_i][jj]
#pragma unroll 8
  for (int e = 0; e < 64; e++) {
    float4 cv = *reinterpret_cast<const float4*>(&ctxT[e][td * 4]);
    float4 wv = *reinterpret_cast<const float4*>(&wrT[e][tj * 4]);
    float ca[4] = {cv.x, cv.y, cv.z, cv.w};
    float wa[4] = {wv.x, wv.y, wv.z, wv.w};
#pragma unroll
    for (int i = 0; i < 4; i++)
#pragma unroll
      for (int jj = 0; jj < 4; jj++) acc[i][jj] += ca[i] * wa[jj];
  }
  float zi[4] = {zinv[td * 4], zinv[td * 4 + 1], zinv[td * 4 + 2], zinv[td * 4 + 3]};
#pragma unroll
  for (int jj = 0; jj < 4; jj++) {
    ushort4 u;
    u.x = f2bf(acc[0][jj] * zi[0]);
    u.y = f2bf(acc[1][jj] * zi[1]);
    u.z = f2bf(acc[2][jj] * zi[2]);
    u.w = f2bf(acc[3][jj] * zi[3]);
    *reinterpret_cast<ushort4*>(
        &Mt[(size_t)(b * 512 + jc * 64 + tj * 4 + jj) * 1024 + cbase + td * 4]) = u;
  }
}

// ---------------------------------------------------------------------------
extern "C" void kernel_launch(void* const* d_in, const int* in_sizes, int n_in,
                              void* d_out, int out_size, void* d_ws, size_t ws_size,
                              hipStream_t stream) {
  const float* f2 = (const float*)d_in[0];
  const float* f3 = (const float*)d_in[1];
  const float* f4 = (const float*)d_in[2];
  const float* f2pe = (const float*)d_in[3];
  const float* f3pe = (const float*)d_in[4];
  const float* f4pe = (const float*)d_in[5];
  const float* Wq1 = (const float*)d_in[6];
  const float* bq1 = (const float*)d_in[7];
  const float* Wk1 = (const float*)d_in[8];
  const float* bk1 = (const float*)d_in[9];
  const float* Wv1 = (const float*)d_in[10];
  const float* bv1 = (const float*)d_in[11];
  const float* Wq2 = (const float*)d_in[12];
  const float* bq2 = (const float*)d_in[13];
  const float* Wk2 = (const float*)d_in[14];
  const float* bk2 = (const float*)d_in[15];
  const float* Wv2 = (const float*)d_in[16];
  const float* bv2 = (const float*)d_in[17];
  const float* Wr = (const float*)d_in[18];
  const float* br = (const float*)d_in[19];

  char* ws = (char*)d_ws;
  // Region 0: E bf16 [32768,1024]
  ushort_t* E = (ushort_t*)(ws + 0);                       // 67,108,864 B
  // Region 1 (reused over time): f2p -> {f3p,f3b,f4p,f4b} -> {ks3,ks4,ctx}
  char* R1 = ws + 67108864;                                // 33,554,432 B
  ushort_t* f2p = (ushort_t*)R1;
  ushort_t* f3p = (ushort_t*)R1;
  ushort_t* f3b = (ushort_t*)(R1 + 8388608);
  ushort_t* f4p = (ushort_t*)(R1 + 16777216);
  ushort_t* f4b = (ushort_t*)(R1 + 18874368);
  ushort_t* ks3 = (ushort_t*)R1;
  ushort_t* ks4 = (ushort_t*)(R1 + 8388608);
  float* ctx = (float*)(R1 + 10485760);                    // 2,097,152 B fp32
  // Region 2: raw kv GEMM outputs (bf16)
  char* R2 = ws + 100663296;                               // 20,971,520 B
  ushort_t* k3r = (ushort_t*)R2;
  ushort_t* v3b = (ushort_t*)(R2 + 8388608);
  ushort_t* k4r = (ushort_t*)(R2 + 16777216);
  ushort_t* v4b = (ushort_t*)(R2 + 18874368);
  // Region 3: weights bf16, Mt, Z, bqcat
  char* R3 = ws + 121634816;
  ushort_t* WqB = (ushort_t*)R3;                           // 1,048,576
  ushort_t* Wk1B = (ushort_t*)(R3 + 1048576);
  ushort_t* Wv1B = (ushort_t*)(R3 + 1572864);
  ushort_t* Wk2B = (ushort_t*)(R3 + 2097152);
  ushort_t* Wv2B = (ushort_t*)(R3 + 2621440);
  ushort_t* Mt = (ushort_t*)(R3 + 3145728);                // 8,388,608
  float* Z = (float*)(R3 + 11534336);                      // 32,768
  float* bqc = (float*)(R3 + 11567104);                    // 4,096

  // ---- prep ----
  hipMemsetAsync(Z, 0, 8 * 1024 * sizeof(float), stream);
  hipMemcpyAsync(bqc, bq1, 512 * sizeof(float), hipMemcpyDeviceToDevice, stream);
  hipMemcpyAsync(bqc + 512, bq2, 512 * sizeof(float), hipMemcpyDeviceToDevice, stream);

  addcvt_kernel<<<16384, 256, 0, stream>>>(f2, f2pe, f2p, 4194304);          // f2p
  addcvt_kernel<<<256, 256, 0, stream>>>(Wq1, nullptr, WqB, 65536);          // Wq cat
  addcvt_kernel<<<256, 256, 0, stream>>>(Wq2, nullptr, WqB + 262144, 65536);
  addcvt_kernel<<<256, 256, 0, stream>>>(Wk1, nullptr, Wk1B, 65536);
  addcvt_kernel<<<256, 256, 0, stream>>>(Wv1, nullptr, Wv1B, 65536);
  addcvt_kernel<<<256, 256, 0, stream>>>(Wk2, nullptr, Wk2B, 65536);
  addcvt_kernel<<<256, 256, 0, stream>>>(Wv2, nullptr, Wv2B, 65536);

  // ---- G1: E = exp(f2p @ WqB^T + bqc), Z colsums ----
  gemm_bf16<0><<<dim3(8, 256), 256, 0, stream>>>(f2p, WqB, bqc, E, Z,
                                                 32768, 1024, 512, 0, 0);

  // ---- kv inputs (reuse R1 — f2p is dead now) ----
  addcvt_kernel<<<4096, 256, 0, stream>>>(f3, f3pe, f3p, 1048576);
  addcvt_kernel<<<4096, 256, 0, stream>>>(f3, nullptr, f3b, 1048576);
  addcvt_kernel<<<1024, 256, 0, stream>>>(f4, f4pe, f4p, 262144);
  addcvt_kernel<<<1024, 256, 0, stream>>>(f4, nullptr, f4b, 262144);

  // ---- kv GEMMs ----
  gemm_bf16<1><<<dim3(4, 64), 256, 0, stream>>>(f3p, Wk1B, bk1, k3r, nullptr,
                                                8192, 512, 512, 0, 0);
  gemm_bf16<1><<<dim3(4, 64), 256, 0, stream>>>(f3b, Wv1B, bv1, v3b, nullptr,
                                                8192, 512, 512, 0, 0);
  gemm_bf16<1><<<dim3(4, 16), 256, 0, stream>>>(f4p, Wk2B, bk2, k4r, nullptr,
                                                2048, 512, 512, 0, 0);
  gemm_bf16<1><<<dim3(4, 16), 256, 0, stream>>>(f4b, Wv2B, bv2, v4b, nullptr,
                                                2048, 512, 512, 0, 0);

  // ---- zero ctx accumulators (after kv GEMMs consumed overlapping R1 bufs) ----
  hipMemsetAsync(ctx, 0, 2097152, stream);

  // ---- channel softmax of k (per row, per 64-ch head group) ----
  softmax64_kernel<<<16384, 256, 0, stream>>>(k3r, ks3, 65536);
  softmax64_kernel<<<4096, 256, 0, stream>>>(k4r, ks4, 16384);

  // ---- ctx = ks^T v  per (b,h), chunked over n with atomic accumulation ----
  ctx_kernel<<<256, 256, 0, stream>>>(ks3, v3b, ctx, 1024, 4);
  ctx_kernel<<<64, 256, 0, stream>>>(ks4, v4b, ctx + 262144, 256, 1);

  // ---- fold ctx, Wr, 1/Z into per-batch Mt[b][j][c] ----
  fold_kernel<<<1024, 256, 0, stream>>>(ctx, Wr, Z, Mt);

  // ---- G2: out = E @ Mt^T + br  (per-batch Bt) ----
  gemm_bf16<2><<<dim3(4, 256), 256, 0, stream>>>(E, Mt, br, (float*)d_out, nullptr,
                                                 32768, 512, 1024, 32, 524288);
}

// Round 3
// 256.256 us; speedup vs baseline: 2.6816x; 1.2668x over previous
//
#include <hip/hip_runtime.h>

typedef unsigned short ushort_t;
typedef unsigned int uint32;
typedef __attribute__((ext_vector_type(8))) short short8;
typedef __attribute__((ext_vector_type(4))) float f32x4;

static __device__ __forceinline__ ushort_t f2bf(float f) {
  uint32 u = __builtin_bit_cast(uint32, f);
  u += 0x7fffu + ((u >> 16) & 1u);   // round-to-nearest-even
  return (ushort_t)(u >> 16);
}
static __device__ __forceinline__ float bf2f(ushort_t h) {
  return __builtin_bit_cast(float, (uint32)h << 16);
}

static __device__ __forceinline__ void gload_lds16(const ushort_t* g, ushort_t* l) {
  __builtin_amdgcn_global_load_lds(
      (const __attribute__((address_space(1))) uint32*)g,
      (__attribute__((address_space(3))) uint32*)l, 16, 0, 0);
}

// ---------------------------------------------------------------------------
// Elementwise: out_bf16 = bf16(a [+ b]) , processes 4 floats/thread
// ---------------------------------------------------------------------------
__global__ void addcvt_kernel(const float* __restrict__ a, const float* __restrict__ b,
                              ushort_t* __restrict__ o, int n4) {
  int i = blockIdx.x * 256 + threadIdx.x;
  if (i >= n4) return;
  float4 va = reinterpret_cast<const float4*>(a)[i];
  if (b != nullptr) {
    float4 vb = reinterpret_cast<const float4*>(b)[i];
    va.x += vb.x; va.y += vb.y; va.z += vb.z; va.w += vb.w;
  }
  ushort4 u;
  u.x = f2bf(va.x); u.y = f2bf(va.y); u.z = f2bf(va.z); u.w = f2bf(va.w);
  reinterpret_cast<ushort4*>(o)[i] = u;
}

// ---------------------------------------------------------------------------
// Shared GEMM core: 128x128 tile, 4 waves, BK=64, global_load_lds staging.
// LDS layout: row-major 128 x 128B, XOR-swizzled byte ^= ((row&7)<<4).
// gload_lds writes lane-linear (base + lane*16), so the SOURCE is
// pre-inverse-swizzled: within each 8-row/1KB segment, lane l stores LDS slot
// (row=l>>3, g=l&7) and must fetch global slot g^(l>>3)  (XOR involution).
// ---------------------------------------------------------------------------
static __device__ __forceinline__ void gemm_core(
    const ushort_t* __restrict__ A, const ushort_t* __restrict__ Bt,
    int K, int mBase, int nBase, ushort_t* As, ushort_t* Bs, f32x4 acc[4][4]) {
  const int t = threadIdx.x;
  const int w = t >> 6, l = t & 63;
  const int l15 = l & 15, l4 = l >> 4;
  const int rowInSeg = l >> 3;
  const int srcOff = ((l & 7) ^ rowInSeg) << 3;   // elements within the row's 64
  const int wm = (w >> 1) * 64, wn = (w & 1) * 64;

  for (int k0 = 0; k0 < K; k0 += 64) {
#pragma unroll
    for (int i = 0; i < 4; i++) {
      int seg = w * 4 + i;                         // 16 segments of 8 rows
      int row = seg * 8 + rowInSeg;
      gload_lds16(A + (size_t)(mBase + row) * K + k0 + srcOff, As + seg * 512);
      gload_lds16(Bt + (size_t)(nBase + row) * K + k0 + srcOff, Bs + seg * 512);
    }
    __syncthreads();
#pragma unroll
    for (int kk = 0; kk < 2; kk++) {
      short8 af[4], bfr[4];
      const int kb = kk * 64 + l4 * 16;
#pragma unroll
      for (int f = 0; f < 4; f++) {
        int rowA = wm + f * 16 + l15;
        af[f] = *reinterpret_cast<const short8*>(
            reinterpret_cast<const char*>(As) + rowA * 128 + (kb ^ ((rowA & 7) << 4)));
        int rowB = wn + f * 16 + l15;
        bfr[f] = *reinterpret_cast<const short8*>(
            reinterpret_cast<const char*>(Bs) + rowB * 128 + (kb ^ ((rowB & 7) << 4)));
      }
#pragma unroll
      for (int fm = 0; fm < 4; fm++)
#pragma unroll
        for (int fn = 0; fn < 4; fn++)
          acc[fm][fn] = __builtin_amdgcn_mfma_f32_16x16x32_bf16(af[fm], bfr[fn], acc[fm][fn], 0, 0, 0);
    }
    __syncthreads();
  }
}

// ---------------------------------------------------------------------------
// G1: E = exp(f2p @ WqB^T + bqc) -> bf16, column sums into Z[batch*1024+col].
// 1D grid 2048 = 256 m-tiles x 8 n-tiles, XCD-chunked swizzle.
// ---------------------------------------------------------------------------
__global__ __launch_bounds__(256, 2)
void gemm_g1(const ushort_t* __restrict__ A, const ushort_t* __restrict__ Bt,
             const float* __restrict__ bias, ushort_t* __restrict__ E,
             float* __restrict__ Z) {
  __shared__ ushort_t As[8192], Bs[8192];
  const int bid = blockIdx.x;
  const int swz = (bid & 7) * 256 + (bid >> 3);    // 2048 % 8 == 0: bijective
  const int mBase = (swz >> 3) * 128, nBase = (swz & 7) * 128;
  const int t = threadIdx.x, w = t >> 6, lane = t & 63;
  const int l15 = lane & 15, l4 = lane >> 4;
  const int wm = (w >> 1) * 64, wn = (w & 1) * 64;

  f32x4 acc[4][4];
#pragma unroll
  for (int i = 0; i < 4; i++)
#pragma unroll
    for (int j = 0; j < 4; j++) acc[i][j] = (f32x4){0.f, 0.f, 0.f, 0.f};

  gemm_core(A, Bt, 512, mBase, nBase, As, Bs, acc);

  const int N = 1024;
#pragma unroll
  for (int fn = 0; fn < 4; fn++) {
    int col = nBase + wn + fn * 16 + l15;
    float bcol = bias[col];
    float csum = 0.f;
#pragma unroll
    for (int fm = 0; fm < 4; fm++) {
#pragma unroll
      for (int r = 0; r < 4; r++) {
        int row = mBase + wm + fm * 16 + l4 * 4 + r;
        float e = __expf(acc[fm][fn][r] + bcol);
        E[(size_t)row * N + col] = f2bf(e);
        csum += e;
      }
    }
    csum += __shfl_xor(csum, 16);
    csum += __shfl_xor(csum, 32);
    if (l4 == 0) atomicAdd(&Z[(mBase >> 12) * 1024 + col], csum);
  }
}

// ---------------------------------------------------------------------------
// KV quad: all four kv GEMMs (N=512, K=512) in one 640-block launch.
// op0 f3k (softmax epilogue), op1 f3v, op2 f4k (softmax), op3 f4v.
// Softmax: per output row, per 64-col head group = (4 fn regs) x (16 l15 lanes).
// ---------------------------------------------------------------------------
__global__ __launch_bounds__(256, 2)
void kv_quad(const ushort_t* __restrict__ f3p, const ushort_t* __restrict__ f3b,
             const ushort_t* __restrict__ f4p, const ushort_t* __restrict__ f4b,
             const ushort_t* __restrict__ Wk1B, const ushort_t* __restrict__ Wv1B,
             const ushort_t* __restrict__ Wk2B, const ushort_t* __restrict__ Wv2B,
             const float* __restrict__ bk1, const float* __restrict__ bv1,
             const float* __restrict__ bk2, const float* __restrict__ bv2,
             ushort_t* __restrict__ ks3, ushort_t* __restrict__ v3,
             ushort_t* __restrict__ ks4, ushort_t* __restrict__ v4) {
  __shared__ ushort_t As[8192], Bs[8192];
  const int id = blockIdx.x;
  const ushort_t* A; const ushort_t* Bt; const float* bias; ushort_t* out;
  bool doSM; int loc;
  if (id < 256)      { A = f3p; Bt = Wk1B; bias = bk1; out = ks3; doSM = true;  loc = id; }
  else if (id < 512) { A = f3b; Bt = Wv1B; bias = bv1; out = v3;  doSM = false; loc = id - 256; }
  else if (id < 576) { A = f4p; Bt = Wk2B; bias = bk2; out = ks4; doSM = true;  loc = id - 512; }
  else               { A = f4b; Bt = Wv2B; bias = bv2; out = v4;  doSM = false; loc = id - 576; }
  const int nBase = (loc & 3) * 128, mBase = (loc >> 2) * 128;
  const int t = threadIdx.x, w = t >> 6, lane = t & 63;
  const int l15 = lane & 15, l4 = lane >> 4;
  const int wm = (w >> 1) * 64, wn = (w & 1) * 64;

  f32x4 acc[4][4];
#pragma unroll
  for (int i = 0; i < 4; i++)
#pragma unroll
    for (int j = 0; j < 4; j++) acc[i][j] = (f32x4){0.f, 0.f, 0.f, 0.f};

  gemm_core(A, Bt, 512, mBase, nBase, As, Bs, acc);

  const int N = 512;
  float bcol[4];
#pragma unroll
  for (int fn = 0; fn < 4; fn++) bcol[fn] = bias[nBase + wn + fn * 16 + l15];

  if (doSM) {
#pragma unroll
    for (int fm = 0; fm < 4; fm++) {
#pragma unroll
      for (int r = 0; r < 4; r++) {
        float x[4], m = -1e30f;
#pragma unroll
        for (int fn = 0; fn < 4; fn++) { x[fn] = acc[fm][fn][r] + bcol[fn]; m = fmaxf(m, x[fn]); }
        m = fmaxf(m, __shfl_xor(m, 1));
        m = fmaxf(m, __shfl_xor(m, 2));
        m = fmaxf(m, __shfl_xor(m, 4));
        m = fmaxf(m, __shfl_xor(m, 8));
        float s = 0.f;
#pragma unroll
        for (int fn = 0; fn < 4; fn++) { x[fn] = __expf(x[fn] - m); s += x[fn]; }
        s += __shfl_xor(s, 1);
        s += __shfl_xor(s, 2);
        s += __shfl_xor(s, 4);
        s += __shfl_xor(s, 8);
        float inv = 1.f / s;
        int row = mBase + wm + fm * 16 + l4 * 4 + r;
#pragma unroll
        for (int fn = 0; fn < 4; fn++)
          out[(size_t)row * N + nBase + wn + fn * 16 + l15] = f2bf(x[fn] * inv);
      }
    }
  } else {
#pragma unroll
    for (int fn = 0; fn < 4; fn++) {
      int col = nBase + wn + fn * 16 + l15;
#pragma unroll
      for (int fm = 0; fm < 4; fm++)
#pragma unroll
        for (int r = 0; r < 4; r++) {
          int row = mBase + wm + fm * 16 + l4 * 4 + r;
          out[(size_t)row * N + col] = f2bf(acc[fm][fn][r] + bcol[fn]);
        }
    }
  }
}

// ---------------------------------------------------------------------------
// G2: out_fp32 = E @ Mt(batch)^T + br.  1D grid 1024 = 256 m-tiles x 4 n-tiles,
// XCD-chunked swizzle (each XCD handles exactly one batch -> Mt pins in L2).
// ---------------------------------------------------------------------------
__global__ __launch_bounds__(256, 2)
void gemm_g2(const ushort_t* __restrict__ E, const ushort_t* __restrict__ Mt,
             const float* __restrict__ bias, float* __restrict__ C) {
  __shared__ ushort_t As[8192], Bs[8192];
  const int bid = blockIdx.x;
  const int swz = (bid & 7) * 128 + (bid >> 3);    // 1024 % 8 == 0: bijective
  const int tx = swz & 3, ty = swz >> 2;
  const int mBase = ty * 128, nBase = tx * 128;
  const ushort_t* Btb = Mt + (size_t)(ty >> 5) * 524288;
  const int t = threadIdx.x, w = t >> 6, lane = t & 63;
  const int l15 = lane & 15, l4 = lane >> 4;
  const int wm = (w >> 1) * 64, wn = (w & 1) * 64;

  f32x4 acc[4][4];
#pragma unroll
  for (int i = 0; i < 4; i++)
#pragma unroll
    for (int j = 0; j < 4; j++) acc[i][j] = (f32x4){0.f, 0.f, 0.f, 0.f};

  gemm_core(E, Btb, 1024, mBase, nBase, As, Bs, acc);

  const int N = 512;
#pragma unroll
  for (int fn = 0; fn < 4; fn++) {
    int col = nBase + wn + fn * 16 + l15;
    float bcol = bias[col];
#pragma unroll
    for (int fm = 0; fm < 4; fm++)
#pragma unroll
      for (int r = 0; r < 4; r++) {
        int row = mBase + wm + fm * 16 + l4 * 4 + r;
        C[(size_t)row * N + col] = acc[fm][fn][r] + bcol;
      }
  }
}

// ---------------------------------------------------------------------------
// ctx[bh,d,e] += sum_{n in chunk} ks[b,n,h*64+d] * v[b,n,h*64+e]
// ---------------------------------------------------------------------------
__global__ __launch_bounds__(256)
void ctx_kernel(const ushort_t* __restrict__ ks, const ushort_t* __restrict__ v,
                float* __restrict__ ctxOut, int Nk, int nChunks) {
  __shared__ float ks_s[64][68];
  __shared__ float v_s[64][68];
  int bh = blockIdx.x / nChunks;
  int chunk = blockIdx.x - bh * nChunks;
  int b = bh >> 3, h = bh & 7;
  int t = threadIdx.x;
  int td = t & 15, te = t >> 4;
  float acc[4][4] = {};
  size_t rowBase = (size_t)b * Nk + chunk * 256;
  for (int n0 = 0; n0 < 256; n0 += 64) {
#pragma unroll
    for (int i = 0; i < 16; i++) {
      int idx = i * 256 + t;
      int n = idx >> 6, d = idx & 63;
      size_t g = (rowBase + n0 + n) * 512 + h * 64 + d;
      ks_s[n][d] = bf2f(ks[g]);
      v_s[n][d] = bf2f(v[g]);
    }
    __syncthreads();
#pragma unroll 8
    for (int n = 0; n < 64; n++) {
      float4 cv = *reinterpret_cast<const float4*>(&ks_s[n][td * 4]);
      float4 vv = *reinterpret_cast<const float4*>(&v_s[n][te * 4]);
      float ca[4] = {cv.x, cv.y, cv.z, cv.w};
      float va[4] = {vv.x, vv.y, vv.z, vv.w};
#pragma unroll
      for (int i = 0; i < 4; i++)
#pragma unroll
        for (int j = 0; j < 4; j++) acc[i][j] += ca[i] * va[j];
    }
    __syncthreads();
  }
  float* dst = ctxOut + (size_t)bh * 4096;
#pragma unroll
  for (int i = 0; i < 4; i++)
#pragma unroll
    for (int j = 0; j < 4; j++)
      atomicAdd(&dst[(td * 4 + i) * 64 + te * 4 + j], acc[i][j]);
}

// ---------------------------------------------------------------------------
// Fold: Mt[b][j][c] = (sum_e ctx[branch,b,h,d,e]*Wr[j, branch*512+h*64+e]) / Z[b,c]
// ---------------------------------------------------------------------------
__global__ __launch_bounds__(256)
void fold_kernel(const float* __restrict__ ctx, const float* __restrict__ Wr,
                 const float* __restrict__ Z, ushort_t* __restrict__ Mt) {
  __shared__ float ctxT[64][68];   // [e][d]
  __shared__ float wrT[64][68];    // [e][jl]
  __shared__ float zinv[64];
  int blk = blockIdx.x;
  int jc = blk & 7;
  int h = (blk >> 3) & 7;
  int branch = (blk >> 6) & 1;
  int b = blk >> 7;
  int t = threadIdx.x;
  int cbase = branch * 512 + h * 64;
  const float* csrc = ctx + (size_t)(branch * 64 + b * 8 + h) * 4096;
#pragma unroll
  for (int i = 0; i < 16; i++) {
    int idx = i * 256 + t;
    int d = idx >> 6, e = idx & 63;
    ctxT[e][d] = csrc[d * 64 + e];
  }
#pragma unroll
  for (int i = 0; i < 16; i++) {
    int idx = i * 256 + t;
    int jl = idx >> 6, e = idx & 63;
    wrT[e][jl] = Wr[(size_t)(jc * 64 + jl) * 1024 + cbase + e];
  }
  if (t < 64) zinv[t] = 1.0f / Z[b * 1024 + cbase + t];
  __syncthreads();
  int td = t & 15, tj = t >> 4;
  float acc[4][4] = {};   // [d_i][jj]
#pragma unroll 8
  for (int e = 0; e < 64; e++) {
    float4 cv = *reinterpret_cast<const float4*>(&ctxT[e][td * 4]);
    float4 wv = *reinterpret_cast<const float4*>(&wrT[e][tj * 4]);
    float ca[4] = {cv.x, cv.y, cv.z, cv.w};
    float wa[4] = {wv.x, wv.y, wv.z, wv.w};
#pragma unroll
    for (int i = 0; i < 4; i++)
#pragma unroll
      for (int jj = 0; jj < 4; jj++) acc[i][jj] += ca[i] * wa[jj];
  }
  float zi[4] = {zinv[td * 4], zinv[td * 4 + 1], zinv[td * 4 + 2], zinv[td * 4 + 3]};
#pragma unroll
  for (int jj = 0; jj < 4; jj++) {
    ushort4 u;
    u.x = f2bf(acc[0][jj] * zi[0]);
    u.y = f2bf(acc[1][jj] * zi[1]);
    u.z = f2bf(acc[2][jj] * zi[2]);
    u.w = f2bf(acc[3][jj] * zi[3]);
    *reinterpret_cast<ushort4*>(
        &Mt[(size_t)(b * 512 + jc * 64 + tj * 4 + jj) * 1024 + cbase + td * 4]) = u;
  }
}

// ---------------------------------------------------------------------------
extern "C" void kernel_launch(void* const* d_in, const int* in_sizes, int n_in,
                              void* d_out, int out_size, void* d_ws, size_t ws_size,
                              hipStream_t stream) {
  const float* f2 = (const float*)d_in[0];
  const float* f3 = (const float*)d_in[1];
  const float* f4 = (const float*)d_in[2];
  const float* f2pe = (const float*)d_in[3];
  const float* f3pe = (const float*)d_in[4];
  const float* f4pe = (const float*)d_in[5];
  const float* Wq1 = (const float*)d_in[6];
  const float* bq1 = (const float*)d_in[7];
  const float* Wk1 = (const float*)d_in[8];
  const float* bk1 = (const float*)d_in[9];
  const float* Wv1 = (const float*)d_in[10];
  const float* bv1 = (const float*)d_in[11];
  const float* Wq2 = (const float*)d_in[12];
  const float* bq2 = (const float*)d_in[13];
  const float* Wk2 = (const float*)d_in[14];
  const float* bk2 = (const float*)d_in[15];
  const float* Wv2 = (const float*)d_in[16];
  const float* bv2 = (const float*)d_in[17];
  const float* Wr = (const float*)d_in[18];
  const float* br = (const float*)d_in[19];

  char* ws = (char*)d_ws;
  // Region 0: E bf16 [32768,1024]
  ushort_t* E = (ushort_t*)(ws + 0);                       // 67,108,864 B
  // Region 1: kv GEMM inputs (f2p earlier), then ctx after kv_quad completes
  char* R1 = ws + 67108864;                                // 33,554,432 B
  ushort_t* f2p = (ushort_t*)R1;
  ushort_t* f3p = (ushort_t*)R1;
  ushort_t* f3b = (ushort_t*)(R1 + 8388608);
  ushort_t* f4p = (ushort_t*)(R1 + 16777216);
  ushort_t* f4b = (ushort_t*)(R1 + 18874368);
  float* ctx = (float*)(R1 + 10485760);                    // 2,097,152 B (after kv)
  // Region 2: kv GEMM outputs (softmaxed k + v, bf16) — no overlap with R1
  char* R2 = ws + 100663296;                               // 20,971,520 B
  ushort_t* ks3 = (ushort_t*)R2;
  ushort_t* v3b = (ushort_t*)(R2 + 8388608);
  ushort_t* ks4 = (ushort_t*)(R2 + 16777216);
  ushort_t* v4b = (ushort_t*)(R2 + 18874368);
  // Region 3: weights bf16, Mt, Z, bqcat
  char* R3 = ws + 121634816;
  ushort_t* WqB = (ushort_t*)R3;                           // 1,048,576
  ushort_t* Wk1B = (ushort_t*)(R3 + 1048576);
  ushort_t* Wv1B = (ushort_t*)(R3 + 1572864);
  ushort_t* Wk2B = (ushort_t*)(R3 + 2097152);
  ushort_t* Wv2B = (ushort_t*)(R3 + 2621440);
  ushort_t* Mt = (ushort_t*)(R3 + 3145728);                // 8,388,608
  float* Z = (float*)(R3 + 11534336);                      // 32,768
  float* bqc = (float*)(R3 + 11567104);                    // 4,096

  // ---- prep ----
  hipMemsetAsync(Z, 0, 8 * 1024 * sizeof(float), stream);
  hipMemcpyAsync(bqc, bq1, 512 * sizeof(float), hipMemcpyDeviceToDevice, stream);
  hipMemcpyAsync(bqc + 512, bq2, 512 * sizeof(float), hipMemcpyDeviceToDevice, stream);

  addcvt_kernel<<<16384, 256, 0, stream>>>(f2, f2pe, f2p, 4194304);          // f2p
  addcvt_kernel<<<256, 256, 0, stream>>>(Wq1, nullptr, WqB, 65536);          // Wq cat
  addcvt_kernel<<<256, 256, 0, stream>>>(Wq2, nullptr, WqB + 262144, 65536);
  addcvt_kernel<<<256, 256, 0, stream>>>(Wk1, nullptr, Wk1B, 65536);
  addcvt_kernel<<<256, 256, 0, stream>>>(Wv1, nullptr, Wv1B, 65536);
  addcvt_kernel<<<256, 256, 0, stream>>>(Wk2, nullptr, Wk2B, 65536);
  addcvt_kernel<<<256, 256, 0, stream>>>(Wv2, nullptr, Wv2B, 65536);

  // ---- G1: E = exp(f2p @ WqB^T + bqc), Z colsums ----
  gemm_g1<<<2048, 256, 0, stream>>>(f2p, WqB, bqc, E, Z);

  // ---- kv inputs (reuse R1 — f2p is dead now) ----
  addcvt_kernel<<<4096, 256, 0, stream>>>(f3, f3pe, f3p, 1048576);
  addcvt_kernel<<<4096, 256, 0, stream>>>(f3, nullptr, f3b, 1048576);
  addcvt_kernel<<<1024, 256, 0, stream>>>(f4, f4pe, f4p, 262144);
  addcvt_kernel<<<1024, 256, 0, stream>>>(f4, nullptr, f4b, 262144);

  // ---- all four kv GEMMs in one launch, k-softmax fused in epilogue ----
  kv_quad<<<640, 256, 0, stream>>>(f3p, f3b, f4p, f4b,
                                   Wk1B, Wv1B, Wk2B, Wv2B,
                                   bk1, bv1, bk2, bv2,
                                   ks3, v3b, ks4, v4b);

  // ---- zero ctx accumulators (R1 is dead after kv_quad) ----
  hipMemsetAsync(ctx, 0, 2097152, stream);

  // ---- ctx = ks^T v  per (b,h), chunked over n with atomic accumulation ----
  ctx_kernel<<<256, 256, 0, stream>>>(ks3, v3b, ctx, 1024, 4);
  ctx_kernel<<<64, 256, 0, stream>>>(ks4, v4b, ctx + 262144, 256, 1);

  // ---- fold ctx, Wr, 1/Z into per-batch Mt[b][j][c] ----
  fold_kernel<<<1024, 256, 0, stream>>>(ctx, Wr, Z, Mt);

  // ---- G2: out = E @ Mt^T + br  (per-batch Bt) ----
  gemm_g2<<<1024, 256, 0, stream>>>(E, Mt, br, (float*)d_out);
}